// Round 4
// baseline (225.723 us; speedup 1.0000x reference)
//
#include <hip/hip_runtime.h>
#include <math.h>

// b=4,n=2048 -> 8192 rows; d=1024; h=8; e=16; cs=2048. Output int32 [8192,8].
// argmax_c q.cbn_c == argmax_c ((x.W - mu*colsum(W)) . cbn_c): LN 1/sigma and
// q-norm are positive per-(row,head) scalars -> cancel. Codebook normalized fp64.

__device__ __forceinline__ void stage16(const float* g, float* lds_base) {
  __builtin_amdgcn_global_load_lds(
      (const __attribute__((address_space(1))) void*)g,
      (__attribute__((address_space(3))) void*)lds_base, 16, 0, 0);
}

// ---------------- K1: normalize codebook (fp64 internally) ----------------
__global__ __launch_bounds__(256) void k_cbnorm(const float* __restrict__ cb,
                                                float* __restrict__ cbn) {
  int v = blockIdx.x * 256 + threadIdx.x;
  const float4* p = (const float4*)(cb + (size_t)v * 16);
  float4 q0 = p[0], q1 = p[1], q2 = p[2], q3 = p[3];
  float f[16] = {q0.x,q0.y,q0.z,q0.w, q1.x,q1.y,q1.z,q1.w,
                 q2.x,q2.y,q2.z,q2.w, q3.x,q3.y,q3.z,q3.w};
  double s = 0.0;
#pragma unroll
  for (int i = 0; i < 16; ++i) s += (double)f[i] * (double)f[i];
  double inv = 1.0 / sqrt(s + 1e-12);
  float r[16];
#pragma unroll
  for (int i = 0; i < 16; ++i) r[i] = (float)((double)f[i] * inv);
  float4* o = (float4*)(cbn + (size_t)v * 16);
  float4* rr = (float4*)r;
  o[0] = rr[0]; o[1] = rr[1]; o[2] = rr[2]; o[3] = rr[3];
}

// ---------------- K2: column sums of W --------------------------------------
__global__ __launch_bounds__(256) void k_colsum(const float* __restrict__ W,
                                                float* __restrict__ cs) {
  __shared__ float red[16][17];
  int h = blockIdx.x;
  int e = threadIdx.x & 15, part = threadIdx.x >> 4;
  const float* base = W + h * 16384 + e;
  float s = 0.f;
  int d0 = part * 64;
  for (int i = 0; i < 64; ++i) s += base[(d0 + i) * 16];
  red[e][part] = s;
  __syncthreads();
  if (threadIdx.x < 16) {
    float t = 0.f;
#pragma unroll
    for (int p = 0; p < 16; ++p) t += red[threadIdx.x][p];
    cs[h * 16 + threadIdx.x] = t;
  }
}

// ---------------- K2b: row means of x (memory-bound) ------------------------
__global__ __launch_bounds__(256) void k_mu(const float* __restrict__ x,
                                            float* __restrict__ mu) {
  __shared__ float red[16][17];
  const int t = threadIdx.x;
  const int g = t & 15, tg = t >> 4;
  const int row = blockIdx.x * 16 + tg;
  const float4* xr = (const float4*)(x + (size_t)row * 1024);
  float s = 0.f;
#pragma unroll
  for (int m = 0; m < 16; ++m) {
    float4 v = xr[g + 16 * m];
    s += (v.x + v.y) + (v.z + v.w);
  }
  red[tg][g] = s;
  __syncthreads();
  if (g == 0) {
    float tt = 0.f;
#pragma unroll
    for (int k = 0; k < 16; ++k) tt += red[tg][k];
    mu[row] = tt * (1.0f / 1024.0f);
  }
}

// ---------------- K3: projection GEMM partials (ksplit 8) -------------------
// Grid (64 rowgroups, 8 ks) x 256. Block: 128 rows x 128 cols x K=128,
// 2 chunks of 64 k. Thread (rgg=t>>4, cgg=t&15): rows rgg*8+j, cols
// {4cgg+i, 64+4cgg+i} -> 8x8 acc. All-LDS-b128:
//  sX [row][16 f4-slots], slot = khat ^ ((row>>3)&3)  (XOR swizzle: the 4
//    distinct rows per read land on 4 distinct bank groups; pitch-64 alone
//    would be a structural 4-way conflict).  Staged by stage16 (per-lane
//    global addr carries the swizzle; LDS side is wave-uniform + lane*16).
//  sW [k][32 f4] (pitch 128): col reads are 16 consecutive float4s =>
//    2-way bank alias = free.
__global__ __launch_bounds__(256) void k_proj(const float* __restrict__ x,
                                              const float* __restrict__ W,
                                              float* __restrict__ part) {
  __shared__ __align__(16) float sX[8192];   // 128 rows x 64 k (f4-swizzled)
  __shared__ __align__(16) float sW[8192];   // 64 k x 128 cols
  const int t = threadIdx.x;
  const int lane = t & 63, w = t >> 6;
  const int r0 = blockIdx.x * 128;
  const int ks = blockIdx.y;               // 0..7
  const int rgg = t >> 4;                  // 0..15
  const int cgg = t & 15;                  // 0..15
  const int xv = rgg & 3;                  // row-read XOR swizzle constant

  float acc[8][8];
#pragma unroll
  for (int j = 0; j < 8; ++j)
#pragma unroll
    for (int i = 0; i < 8; ++i) acc[j][i] = 0.f;

  for (int ch = 0; ch < 2; ++ch) {
    const int kbase = ks * 128 + ch * 64;
    __syncthreads();
    // stage sX: 2048 f4 (8 per thread), swizzled
#pragma unroll
    for (int j = 0; j < 8; ++j) {
      int f = lane + 64 * (w + 4 * j);
      int row = f >> 4, s = f & 15;
      int kh = s ^ ((row >> 3) & 3);
      stage16(x + (size_t)(r0 + row) * 1024 + kbase + 4 * kh,
              sX + (w + 4 * j) * 256);
    }
    // stage sW: 2048 f4 (8 per thread), [k][c4] with c4 = h*4+e4
#pragma unroll
    for (int j = 0; j < 8; ++j) {
      int f = lane + 64 * (w + 4 * j);
      int k = f >> 5, c4 = f & 31;
      int h = c4 >> 2, e4 = c4 & 3;
      stage16(W + (size_t)h * 16384 + (size_t)(kbase + k) * 16 + 4 * e4,
              sW + (w + 4 * j) * 256);
    }
    __syncthreads();
#pragma unroll
    for (int kh = 0; kh < 16; ++kh) {
      float4 rv[8];
      const int slot = kh ^ xv;
#pragma unroll
      for (int j = 0; j < 8; ++j)
        rv[j] = ((const float4*)sX)[(rgg * 8 + j) * 16 + slot];
#pragma unroll
      for (int kk = 0; kk < 4; ++kk) {
        float4 cv0 = ((const float4*)sW)[(kh * 4 + kk) * 32 + cgg];
        float4 cv1 = ((const float4*)sW)[(kh * 4 + kk) * 32 + 16 + cgg];
#pragma unroll
        for (int j = 0; j < 8; ++j) {
          float xval = (kk == 0) ? rv[j].x : (kk == 1) ? rv[j].y
                     : (kk == 2) ? rv[j].z : rv[j].w;
          acc[j][0] += xval * cv0.x; acc[j][1] += xval * cv0.y;
          acc[j][2] += xval * cv0.z; acc[j][3] += xval * cv0.w;
          acc[j][4] += xval * cv1.x; acc[j][5] += xval * cv1.y;
          acc[j][6] += xval * cv1.z; acc[j][7] += xval * cv1.w;
        }
      }
    }
  }
  float* po = part + ((size_t)ks * 8192 + r0) * 128;
#pragma unroll
  for (int j = 0; j < 8; ++j) {
    float4 o0 = {acc[j][0], acc[j][1], acc[j][2], acc[j][3]};
    float4 o1 = {acc[j][4], acc[j][5], acc[j][6], acc[j][7]};
    *(float4*)(po + (size_t)(rgg * 8 + j) * 128 + 4 * cgg) = o0;
    *(float4*)(po + (size_t)(rgg * 8 + j) * 128 + 64 + 4 * cgg) = o1;
  }
}

// ---------------- K3b: combine 8 K-slices - mu*colsum -----------------------
__global__ __launch_bounds__(256) void k_combine(const float* __restrict__ part,
                                                 const float* __restrict__ mu,
                                                 const float* __restrict__ csum,
                                                 float* __restrict__ tmat) {
  int idx = blockIdx.x * 256 + threadIdx.x;   // f4 index, 262144 total
  int row = idx >> 5, c4 = (idx & 31) * 4;
  float4 a = {0.f, 0.f, 0.f, 0.f};
#pragma unroll
  for (int s = 0; s < 8; ++s) {
    float4 p = *(const float4*)(part + ((size_t)s * 8192 + row) * 128 + c4);
    a.x += p.x; a.y += p.y; a.z += p.z; a.w += p.w;
  }
  float4 cs = *(const float4*)(csum + c4);
  float m = mu[row];
  float4 o;
  o.x = a.x - m * cs.x; o.y = a.y - m * cs.y;
  o.z = a.z - m * cs.z; o.w = a.w - m * cs.w;
  *(float4*)(tmat + (size_t)row * 128 + c4) = o;
}

// ---------------- K4: argmax partials (rows in registers) -------------------
// Grid (64 rowgroups, 8 heads, 2 halves) x 256. Block: 128 rows x 1024 codes
// (8 tiles of 128). Thread (rg=t>>4, cg=t&15): rows j*16+rg held ENTIRELY in
// registers (8 rows x 16e = 32 f4, loaded once from global; reused across all
// 8 tiles -> no row LDS traffic). Codes staged per tile in e-chunk-major LDS;
// code reads: 16 consecutive f4 per inst = conflict-free. Per-thread code ids
// strictly ascend -> strict '>' = first-max; cross-thread reduce lexicographic.
__global__ __launch_bounds__(256) void k_argmax(const float* __restrict__ tmat,
                                                const float* __restrict__ cbn,
                                                float* __restrict__ amv,
                                                int* __restrict__ ami) {
  __shared__ __align__(16) float sCb[4 * 128 * 4];   // [ec][c] f4
  __shared__ float sRv[128 * 17];
  __shared__ int   sRi[128 * 17];
  const int t = threadIdx.x;
  const int h = blockIdx.y;
  const int half = blockIdx.z;
  const int r0 = blockIdx.x * 128;
  const int rg = t >> 4, cg = t & 15;

  float4 rowreg[8][4];
#pragma unroll
  for (int j = 0; j < 8; ++j) {
    const float* src = tmat + (size_t)(r0 + j * 16 + rg) * 128 + h * 16;
#pragma unroll
    for (int ec = 0; ec < 4; ++ec)
      rowreg[j][ec] = ((const float4*)src)[ec];
  }

  float best[8];
  int   bidx[8];
#pragma unroll
  for (int j = 0; j < 8; ++j) { best[j] = -3.402823466e38f; bidx[j] = 0; }
  const float* cbh = cbn + ((size_t)h * 2048 + half * 1024) * 16;

  for (int tile = 0; tile < 8; ++tile) {
    __syncthreads();
    {  // stage 128 codes x 16 e, e-chunk-major
      int c = t >> 1, hf = t & 1;
      const float* src = cbh + (size_t)(tile * 128 + c) * 16 + hf * 8;
      float4 a = ((const float4*)src)[0];
      float4 b = ((const float4*)src)[1];
      ((float4*)sCb)[(2 * hf) * 128 + c] = a;
      ((float4*)sCb)[(2 * hf + 1) * 128 + c] = b;
    }
    __syncthreads();

#pragma unroll
    for (int i = 0; i < 8; ++i) {
      float4 cv0 = ((const float4*)sCb)[0 * 128 + i * 16 + cg];
      float4 cv1 = ((const float4*)sCb)[1 * 128 + i * 16 + cg];
      float4 cv2 = ((const float4*)sCb)[2 * 128 + i * 16 + cg];
      float4 cv3 = ((const float4*)sCb)[3 * 128 + i * 16 + cg];
      const int idx = half * 1024 + tile * 128 + i * 16 + cg;
#pragma unroll
      for (int j = 0; j < 8; ++j) {
        float s = rowreg[j][0].x * cv0.x + rowreg[j][0].y * cv0.y +
                  rowreg[j][0].z * cv0.z + rowreg[j][0].w * cv0.w +
                  rowreg[j][1].x * cv1.x + rowreg[j][1].y * cv1.y +
                  rowreg[j][1].z * cv1.z + rowreg[j][1].w * cv1.w +
                  rowreg[j][2].x * cv2.x + rowreg[j][2].y * cv2.y +
                  rowreg[j][2].z * cv2.z + rowreg[j][2].w * cv2.w +
                  rowreg[j][3].x * cv3.x + rowreg[j][3].y * cv3.y +
                  rowreg[j][3].z * cv3.z + rowreg[j][3].w * cv3.w;
        if (s > best[j]) { best[j] = s; bidx[j] = idx; }
      }
    }
  }

  __syncthreads();
#pragma unroll
  for (int j = 0; j < 8; ++j) {
    sRv[(j * 16 + rg) * 17 + cg] = best[j];
    sRi[(j * 16 + rg) * 17 + cg] = bidx[j];
  }
  __syncthreads();
  if (t < 128) {
    float bv = -3.402823466e38f; int bi = 0x7fffffff;
#pragma unroll
    for (int k = 0; k < 16; ++k) {
      float v = sRv[t * 17 + k]; int ix = sRi[t * 17 + k];
      if (v > bv || (v == bv && ix < bi)) { bv = v; bi = ix; }
    }
    size_t o = ((size_t)half * 8192 + r0 + t) * 8 + h;
    amv[o] = bv; ami[o] = bi;
  }
}

// ---------------- K5: merge the two code-halves -----------------------------
__global__ __launch_bounds__(256) void k_amred(const float* __restrict__ amv,
                                               const int* __restrict__ ami,
                                               int* __restrict__ out) {
  int i = blockIdx.x * 256 + threadIdx.x;   // 65536
  float v0 = amv[i], v1 = amv[65536 + i];
  int i0 = ami[i], i1 = ami[65536 + i];
  out[i] = (v1 > v0) ? i1 : i0;             // tie -> half0 (lower idx) = first max
}

extern "C" void kernel_launch(void* const* d_in, const int* in_sizes, int n_in,
                              void* d_out, int out_size, void* d_ws, size_t ws_size,
                              hipStream_t stream) {
  (void)in_sizes; (void)n_in; (void)out_size; (void)ws_size;
  const float* x  = (const float*)d_in[0];   // [4,2048,1024]
  const float* rp = (const float*)d_in[1];   // [8,1024,16]
  const float* cb = (const float*)d_in[2];   // [8,2048,16]
  int* out = (int*)d_out;                    // [8192,8] int32

  float* ws   = (float*)d_ws;
  float* cbn  = ws;                          // 262144
  float* csum = ws + 262144;                 // 128
  float* mu   = ws + 262272;                 // 8192
  float* part = ws + 270464;                 // 8*8192*128 = 8388608
  float* tmat = ws + 8659072;                // 1048576
  float* amv  = ws + 9707648;                // 131072
  int*   ami  = (int*)(ws + 9838720);        // 131072  (total ~39.9 MB)

  hipLaunchKernelGGL(k_cbnorm,  dim3(64),        dim3(256), 0, stream, cb, cbn);
  hipLaunchKernelGGL(k_colsum,  dim3(8),         dim3(256), 0, stream, rp, csum);
  hipLaunchKernelGGL(k_mu,      dim3(512),       dim3(256), 0, stream, x, mu);
  hipLaunchKernelGGL(k_proj,    dim3(64, 8),     dim3(256), 0, stream, x, rp, part);
  hipLaunchKernelGGL(k_combine, dim3(1024),      dim3(256), 0, stream, part, mu, csum, tmat);
  hipLaunchKernelGGL(k_argmax,  dim3(64, 8, 2),  dim3(256), 0, stream, tmat, cbn, amv, ami);
  hipLaunchKernelGGL(k_amred,   dim3(256),       dim3(256), 0, stream, amv, ami, out);
}

// Round 5
// 195.211 us; speedup vs baseline: 1.1563x; 1.1563x over previous
//
#include <hip/hip_runtime.h>
#include <math.h>

// b=4,n=2048 -> 8192 rows; d=1024; h=8; e=16; cs=2048. Output int32 [8192,8].
// argmax_c q.cbn_c == argmax_c ((x.W - mu*colsum(W)) . cbn_c): LN 1/sigma and
// q-norm are positive per-(row,head) scalars -> cancel. Codebook normalized fp64.

__device__ __forceinline__ void stage16(const float* g, float* lds_base) {
  __builtin_amdgcn_global_load_lds(
      (const __attribute__((address_space(1))) void*)g,
      (__attribute__((address_space(3))) void*)lds_base, 16, 0, 0);
}

// ---------------- K1: normalize codebook (fp64 internally) ----------------
__global__ __launch_bounds__(256) void k_cbnorm(const float* __restrict__ cb,
                                                float* __restrict__ cbn) {
  int v = blockIdx.x * 256 + threadIdx.x;
  const float4* p = (const float4*)(cb + (size_t)v * 16);
  float4 q0 = p[0], q1 = p[1], q2 = p[2], q3 = p[3];
  float f[16] = {q0.x,q0.y,q0.z,q0.w, q1.x,q1.y,q1.z,q1.w,
                 q2.x,q2.y,q2.z,q2.w, q3.x,q3.y,q3.z,q3.w};
  double s = 0.0;
#pragma unroll
  for (int i = 0; i < 16; ++i) s += (double)f[i] * (double)f[i];
  double inv = 1.0 / sqrt(s + 1e-12);
  float r[16];
#pragma unroll
  for (int i = 0; i < 16; ++i) r[i] = (float)((double)f[i] * inv);
  float4* o = (float4*)(cbn + (size_t)v * 16);
  float4* rr = (float4*)r;
  o[0] = rr[0]; o[1] = rr[1]; o[2] = rr[2]; o[3] = rr[3];
}

// ---------------- K2: column sums of W --------------------------------------
__global__ __launch_bounds__(256) void k_colsum(const float* __restrict__ W,
                                                float* __restrict__ cs) {
  __shared__ float red[16][17];
  int h = blockIdx.x;
  int e = threadIdx.x & 15, part = threadIdx.x >> 4;
  const float* base = W + h * 16384 + e;
  float s = 0.f;
  int d0 = part * 64;
  for (int i = 0; i < 64; ++i) s += base[(d0 + i) * 16];
  red[e][part] = s;
  __syncthreads();
  if (threadIdx.x < 16) {
    float t = 0.f;
#pragma unroll
    for (int p = 0; p < 16; ++p) t += red[threadIdx.x][p];
    cs[h * 16 + threadIdx.x] = t;
  }
}

// ---------------- K2b: row means of x (memory-bound) ------------------------
__global__ __launch_bounds__(256) void k_mu(const float* __restrict__ x,
                                            float* __restrict__ mu) {
  __shared__ float red[16][17];
  const int t = threadIdx.x;
  const int g = t & 15, tg = t >> 4;
  const int row = blockIdx.x * 16 + tg;
  const float4* xr = (const float4*)(x + (size_t)row * 1024);
  float s = 0.f;
#pragma unroll
  for (int m = 0; m < 16; ++m) {
    float4 v = xr[g + 16 * m];
    s += (v.x + v.y) + (v.z + v.w);
  }
  red[tg][g] = s;
  __syncthreads();
  if (g == 0) {
    float tt = 0.f;
#pragma unroll
    for (int k = 0; k < 16; ++k) tt += red[tg][k];
    mu[row] = tt * (1.0f / 1024.0f);
  }
}

// ---------------- K3: projection GEMM partials (ksplit 4) -------------------
// Grid (256 rowgroups, 4 ks) x 256 = 1024 blocks (4/CU). Block: 32 rows x
// 128 cols x K=256, 8 chunks of 32k. Thread (rgg=t>>5 in 0..7, cg=t&31):
// rows rgg*4+j, cols cg*4+i -> 4x4 acc (16 regs).
//  sX [32 rows][8 f4-slots], slot = k4 ^ rgg_of_row (XOR swizzle; per-wave
//    row reads = 2 distinct addrs on 2 distinct bank groups -> free).
//  sW [32 k][128 cols] k-major: col read = 32 consecutive f4 in 512B -> no
//    pathological conflict (pure capacity).
__global__ __launch_bounds__(256) void k_proj(const float* __restrict__ x,
                                              const float* __restrict__ W,
                                              float* __restrict__ part) {
  __shared__ __align__(16) float sX[32 * 32];     // 4 KB
  __shared__ __align__(16) float sW[32 * 128];    // 16 KB
  const int t = threadIdx.x;
  const int lane = t & 63, w = t >> 6;
  const int r0 = blockIdx.x * 32;
  const int ks = blockIdx.y;               // 0..3
  const int rgg = t >> 5;                  // 0..7
  const int cg = t & 31;                   // 0..31

  // staging index precompute
  const int fx = 64 * w + lane;            // sX f4 id 0..255
  const int xrow = fx >> 3, xs = fx & 7;
  const int xk4 = xs ^ ((xrow >> 2) & 7);
  const float* xsrc0 = x + (size_t)(r0 + xrow) * 1024 + ks * 256 + 4 * xk4;

  float acc[4][4];
#pragma unroll
  for (int j = 0; j < 4; ++j)
#pragma unroll
    for (int i = 0; i < 4; ++i) acc[j][i] = 0.f;

  for (int ch = 0; ch < 8; ++ch) {
    const int kbase = ks * 256 + ch * 32;
    __syncthreads();
    // sX: 256 f4, 1 per thread
    stage16(xsrc0 + ch * 32, sX + w * 256);
    // sW: 1024 f4, 4 per thread
#pragma unroll
    for (int i = 0; i < 4; ++i) {
      int f = (4 * w + i) * 64 + lane;
      int k = f >> 5, c4 = f & 31;
      int h = c4 >> 2, e4 = c4 & 3;
      stage16(W + (size_t)h * 16384 + (size_t)(kbase + k) * 16 + 4 * e4,
              sW + (4 * w + i) * 256);
    }
    __syncthreads();
#pragma unroll
    for (int k4 = 0; k4 < 8; ++k4) {
      float4 rv[4];
      const int slot = k4 ^ rgg;
#pragma unroll
      for (int j = 0; j < 4; ++j)
        rv[j] = ((const float4*)sX)[(rgg * 4 + j) * 8 + slot];
#pragma unroll
      for (int kk = 0; kk < 4; ++kk) {
        float4 cv = ((const float4*)sW)[(k4 * 4 + kk) * 32 + cg];
#pragma unroll
        for (int j = 0; j < 4; ++j) {
          float xval = (kk == 0) ? rv[j].x : (kk == 1) ? rv[j].y
                     : (kk == 2) ? rv[j].z : rv[j].w;
          acc[j][0] += xval * cv.x; acc[j][1] += xval * cv.y;
          acc[j][2] += xval * cv.z; acc[j][3] += xval * cv.w;
        }
      }
    }
  }
  float* po = part + ((size_t)ks * 8192 + r0) * 128;
#pragma unroll
  for (int j = 0; j < 4; ++j) {
    float4 o0 = {acc[j][0], acc[j][1], acc[j][2], acc[j][3]};
    *(float4*)(po + (size_t)(rgg * 4 + j) * 128 + 4 * cg) = o0;
  }
}

// ---------------- K3b: combine 4 K-slices - mu*colsum -----------------------
__global__ __launch_bounds__(256) void k_combine(const float* __restrict__ part,
                                                 const float* __restrict__ mu,
                                                 const float* __restrict__ csum,
                                                 float* __restrict__ tmat) {
  int idx = blockIdx.x * 256 + threadIdx.x;   // f4 index, 262144 total
  int row = idx >> 5, c4 = (idx & 31) * 4;
  float4 a = {0.f, 0.f, 0.f, 0.f};
#pragma unroll
  for (int s = 0; s < 4; ++s) {
    float4 p = *(const float4*)(part + ((size_t)s * 8192 + row) * 128 + c4);
    a.x += p.x; a.y += p.y; a.z += p.z; a.w += p.w;
  }
  float4 cs = *(const float4*)(csum + c4);
  float m = mu[row];
  float4 o;
  o.x = a.x - m * cs.x; o.y = a.y - m * cs.y;
  o.z = a.z - m * cs.z; o.w = a.w - m * cs.w;
  *(float4*)(tmat + (size_t)row * 128 + c4) = o;
}

// ---------------- K4: argmax partials ---------------------------------------
// Grid (128 rowgroups, 8 heads, 2 halves) x 256 = 2048 blocks (8/CU grid).
// Block: 64 rows x 1024 codes (8 tiles of 128). Thread (rg=t>>4, cg=t&15):
// rows j*16+rg (j 0..3), codes i*16+cg (i 0..7) -> acc 4x8 = 32 regs.
// sPt [ec][64 r] f4 staged once (4KB); sCb [ec][128 c] f4 per tile (8KB).
// rv: 4 distinct consecutive-f4 addrs/wave -> conflict-free; cv: 16
// consecutive f4 -> 2-way alias = free. Final reduce: shfl_xor width 16
// (threads sharing rows are 16 contiguous lanes) -> no LDS, no barrier.
__global__ __launch_bounds__(256) void k_argmax(const float* __restrict__ tmat,
                                                const float* __restrict__ cbn,
                                                float* __restrict__ amv,
                                                int* __restrict__ ami) {
  __shared__ __align__(16) float sPt[4 * 64 * 4];    // [ec][r] f4, 4 KB
  __shared__ __align__(16) float sCb[4 * 128 * 4];   // [ec][c] f4, 8 KB
  const int t = threadIdx.x;
  const int lane = t & 63, w = t >> 6;
  const int h = blockIdx.y;
  const int half = blockIdx.z;
  const int r0 = blockIdx.x * 64;
  const int rg = t >> 4, cg = t & 15;

  {  // stage 64 rows x 16 e, e-chunk-major: 256 f4, 1/thread (ec == w)
    int r = lane & 63;
    int rr = r;  // f = w*64 + lane -> ec = w, r = lane
    stage16(tmat + (size_t)(r0 + rr) * 128 + h * 16 + w * 4, sPt + w * 256);
  }

  float best[4];
  int   bidx[4];
#pragma unroll
  for (int j = 0; j < 4; ++j) { best[j] = -3.402823466e38f; bidx[j] = 0; }
  const float* cbh = cbn + ((size_t)h * 2048 + half * 1024) * 16;

  for (int tile = 0; tile < 8; ++tile) {
    __syncthreads();
    {  // stage 128 codes x 16 e, e-chunk-major: 512 f4, 2/thread
#pragma unroll
      for (int i = 0; i < 2; ++i) {
        int f = (2 * w + i) * 64 + lane;
        int ec = f >> 7, c = f & 127;
        stage16(cbh + (size_t)(tile * 128 + c) * 16 + ec * 4,
                sCb + (2 * w + i) * 256);
      }
    }
    __syncthreads();

    float acc[4][8];
#pragma unroll
    for (int j = 0; j < 4; ++j)
#pragma unroll
      for (int i = 0; i < 8; ++i) acc[j][i] = 0.f;

#pragma unroll
    for (int ec = 0; ec < 4; ++ec) {
      float4 rv[4];
#pragma unroll
      for (int j = 0; j < 4; ++j)
        rv[j] = ((const float4*)sPt)[ec * 64 + j * 16 + rg];
#pragma unroll
      for (int i = 0; i < 8; ++i) {
        float4 cv = ((const float4*)sCb)[ec * 128 + i * 16 + cg];
#pragma unroll
        for (int j = 0; j < 4; ++j)
          acc[j][i] += rv[j].x * cv.x + rv[j].y * cv.y +
                       rv[j].z * cv.z + rv[j].w * cv.w;
      }
    }

    const int cb0 = half * 1024 + tile * 128 + cg;
#pragma unroll
    for (int j = 0; j < 4; ++j)
#pragma unroll
      for (int i = 0; i < 8; ++i) {
        float v = acc[j][i];
        if (v > best[j]) { best[j] = v; bidx[j] = cb0 + i * 16; }
      }
  }

  // shfl_xor reduce over the 16 lanes sharing each row set
#pragma unroll
  for (int off = 1; off < 16; off <<= 1) {
#pragma unroll
    for (int j = 0; j < 4; ++j) {
      float ov = __shfl_xor(best[j], off, 16);
      int   oi = __shfl_xor(bidx[j], off, 16);
      if (ov > best[j] || (ov == best[j] && oi < bidx[j])) {
        best[j] = ov; bidx[j] = oi;
      }
    }
  }
  if (cg == 0) {
#pragma unroll
    for (int j = 0; j < 4; ++j) {
      size_t o = ((size_t)half * 8192 + r0 + j * 16 + rg) * 8 + h;
      amv[o] = best[j]; ami[o] = bidx[j];
    }
  }
}

// ---------------- K5: merge the two code-halves -----------------------------
__global__ __launch_bounds__(256) void k_amred(const float* __restrict__ amv,
                                               const int* __restrict__ ami,
                                               int* __restrict__ out) {
  int i = blockIdx.x * 256 + threadIdx.x;   // 65536
  float v0 = amv[i], v1 = amv[65536 + i];
  int i0 = ami[i], i1 = ami[65536 + i];
  out[i] = (v1 > v0) ? i1 : i0;             // tie -> half0 (lower idx) = first max
}

extern "C" void kernel_launch(void* const* d_in, const int* in_sizes, int n_in,
                              void* d_out, int out_size, void* d_ws, size_t ws_size,
                              hipStream_t stream) {
  (void)in_sizes; (void)n_in; (void)out_size; (void)ws_size;
  const float* x  = (const float*)d_in[0];   // [4,2048,1024]
  const float* rp = (const float*)d_in[1];   // [8,1024,16]
  const float* cb = (const float*)d_in[2];   // [8,2048,16]
  int* out = (int*)d_out;                    // [8192,8] int32

  float* ws   = (float*)d_ws;
  float* cbn  = ws;                          // 262144
  float* csum = ws + 262144;                 // 128
  float* mu   = ws + 262272;                 // 8192
  float* part = ws + 270464;                 // 4*8192*128 = 4194304
  float* tmat = ws + 4464768;                // 1048576
  float* amv  = ws + 5513344;                // 131072
  int*   ami  = (int*)(ws + 5644416);        // 131072  (~23.1 MB)

  hipLaunchKernelGGL(k_cbnorm,  dim3(64),         dim3(256), 0, stream, cb, cbn);
  hipLaunchKernelGGL(k_colsum,  dim3(8),          dim3(256), 0, stream, rp, csum);
  hipLaunchKernelGGL(k_mu,      dim3(512),        dim3(256), 0, stream, x, mu);
  hipLaunchKernelGGL(k_proj,    dim3(256, 4),     dim3(256), 0, stream, x, rp, part);
  hipLaunchKernelGGL(k_combine, dim3(1024),       dim3(256), 0, stream, part, mu, csum, tmat);
  hipLaunchKernelGGL(k_argmax,  dim3(128, 8, 2),  dim3(256), 0, stream, tmat, cbn, amv, ami);
  hipLaunchKernelGGL(k_amred,   dim3(256),        dim3(256), 0, stream, amv, ami, out);
}

// Round 7
// 156.657 us; speedup vs baseline: 1.4409x; 1.2461x over previous
//
#include <hip/hip_runtime.h>
#include <math.h>

// b=4,n=2048 -> 8192 rows; d=1024; h=8; e=16; cs=2048. Output int32 [8192,8].
// argmax_c q.cbn_c == argmax_c ((x.W - mu*colsum(W)) . cbn_c): LN 1/sigma and
// q-norm are positive per-(row,head) scalars -> cancel. Codebook normalized fp64.
//
// MFMA path: every fp32 operand v is split into 3 bf16 parts h,m,l
// (8+8+8 mantissa bits ~= fp32's 24; bf16 exponent range == fp32 -> NO
// subnormal flushing, unlike the failed fp16-split attempt). Products:
//   v_p*v_c = hh + (hm+mh) + (hl+mm+lh) + O(2^-25)
// packed into 3 K=32 bf16 MFMAs: [h|m].[h|m] -> hh+mm ; [h|m].[m|h] ->
// hm+mh ; [h|l].[l|h] -> hl+lh. Dropped ml/lm/ll ~2^-25 rel (< np fp32 noise).

typedef short bf16x8 __attribute__((ext_vector_type(8)));
typedef float f32x4 __attribute__((ext_vector_type(4)));

__device__ __forceinline__ void stage16(const float* g, float* lds_base) {
  __builtin_amdgcn_global_load_lds(
      (const __attribute__((address_space(1))) void*)g,
      (__attribute__((address_space(3))) void*)lds_base, 16, 0, 0);
}

__device__ __forceinline__ unsigned short f2bf(float f) {
  unsigned u = __builtin_bit_cast(unsigned, f);
  unsigned r = (u + 0x7FFFu + ((u >> 16) & 1u)) >> 16;   // RNE
  return (unsigned short)r;
}
__device__ __forceinline__ float bf2f(unsigned short b) {
  return __builtin_bit_cast(float, (unsigned)b << 16);
}
__device__ __forceinline__ void split3(float v, unsigned short& h,
                                       unsigned short& m, unsigned short& l) {
  h = f2bf(v);
  float r = v - bf2f(h);
  m = f2bf(r);
  float r2 = r - bf2f(m);
  l = f2bf(r2);
}

// ---------------- K1: normalize codebook (fp64) + bf16 3-split --------------
__global__ __launch_bounds__(256) void k_cbnorm(const float* __restrict__ cb,
                                                unsigned short* __restrict__ ch,
                                                unsigned short* __restrict__ cm,
                                                unsigned short* __restrict__ cl) {
  int v = blockIdx.x * 256 + threadIdx.x;      // 0..16383 code vectors
  const float4* p = (const float4*)(cb + (size_t)v * 16);
  float4 q0 = p[0], q1 = p[1], q2 = p[2], q3 = p[3];
  float f[16] = {q0.x,q0.y,q0.z,q0.w, q1.x,q1.y,q1.z,q1.w,
                 q2.x,q2.y,q2.z,q2.w, q3.x,q3.y,q3.z,q3.w};
  double s = 0.0;
#pragma unroll
  for (int i = 0; i < 16; ++i) s += (double)f[i] * (double)f[i];
  double inv = 1.0 / sqrt(s + 1e-12);
  unsigned short vh[16], vm[16], vl[16];
#pragma unroll
  for (int i = 0; i < 16; ++i)
    split3((float)((double)f[i] * inv), vh[i], vm[i], vl[i]);
#pragma unroll
  for (int i = 0; i < 2; ++i) {
    ((bf16x8*)(ch + (size_t)v * 16))[i] = ((bf16x8*)vh)[i];
    ((bf16x8*)(cm + (size_t)v * 16))[i] = ((bf16x8*)vm)[i];
    ((bf16x8*)(cl + (size_t)v * 16))[i] = ((bf16x8*)vl)[i];
  }
}

// ---------------- K2: column sums of W --------------------------------------
__global__ __launch_bounds__(256) void k_colsum(const float* __restrict__ W,
                                                float* __restrict__ cs) {
  __shared__ float red[16][17];
  int h = blockIdx.x;
  int e = threadIdx.x & 15, part = threadIdx.x >> 4;
  const float* base = W + h * 16384 + e;
  float s = 0.f;
  int d0 = part * 64;
  for (int i = 0; i < 64; ++i) s += base[(d0 + i) * 16];
  red[e][part] = s;
  __syncthreads();
  if (threadIdx.x < 16) {
    float t = 0.f;
#pragma unroll
    for (int p = 0; p < 16; ++p) t += red[threadIdx.x][p];
    cs[h * 16 + threadIdx.x] = t;
  }
}

// ---------------- K2b: W transpose + bf16 3-split ---------------------------
// W [8,1024,16] fp32 -> Wth/Wtm/Wtl [128 cols=(h*16+e)][1024 d] bf16.
__global__ __launch_bounds__(256) void k_wsplit(const float* __restrict__ W,
                                                unsigned short* __restrict__ Wth,
                                                unsigned short* __restrict__ Wtm,
                                                unsigned short* __restrict__ Wtl) {
  int idx = blockIdx.x * 256 + threadIdx.x;    // 0..131071
  int d = idx & 1023, col = idx >> 10;
  int h = col >> 4, e = col & 15;
  float v = W[h * 16384 + d * 16 + e];
  unsigned short a, b, c;
  split3(v, a, b, c);
  Wth[(size_t)col * 1024 + d] = a;
  Wtm[(size_t)col * 1024 + d] = b;
  Wtl[(size_t)col * 1024 + d] = c;
}

// ---------------- K2c: row means of x ---------------------------------------
__global__ __launch_bounds__(256) void k_mu(const float* __restrict__ x,
                                            float* __restrict__ mu) {
  __shared__ float red[16][17];
  const int t = threadIdx.x;
  const int g = t & 15, tg = t >> 4;
  const int row = blockIdx.x * 16 + tg;
  const float4* xr = (const float4*)(x + (size_t)row * 1024);
  float s = 0.f;
#pragma unroll
  for (int m = 0; m < 16; ++m) {
    float4 v = xr[g + 16 * m];
    s += (v.x + v.y) + (v.z + v.w);
  }
  red[tg][g] = s;
  __syncthreads();
  if (g == 0) {
    float tt = 0.f;
#pragma unroll
    for (int k = 0; k < 16; ++k) tt += red[tg][k];
    mu[row] = tt * (1.0f / 1024.0f);
  }
}

// ---------------- K3: projection GEMM via bf16-split MFMA -------------------
// Grid (64 rowgroups, 8 ds) x 256. Block: 128 rows x 128 cols x 128 d.
// 4 windows of 32 d. Wave = 32 rows (2 row-tiles of 16). x fp32 staged in LDS
// [oct][row][8], split to bf16 in-register per lane; W-splits staged in LDS
// [arr][oct][col][8]. 16x16x32 bf16 layout: A[m=lane&15][k=quad*8+j],
// B[k][n=lane&15], D[row=quad*4+reg][col=lane&15].
__global__ __launch_bounds__(256) void k_proj(const float* __restrict__ x,
                                              const unsigned short* __restrict__ Wth,
                                              const unsigned short* __restrict__ Wtm,
                                              const unsigned short* __restrict__ Wtl,
                                              float* __restrict__ part) {
  __shared__ __align__(16) float sXf[4096];            // 16 KB: [oct][row][8]
  __shared__ __align__(16) unsigned short sB[12288];   // 24 KB: [a][oct][col][8]
  const int t = threadIdx.x;
  const int lane = t & 63, w = t >> 6;
  const int r0 = blockIdx.x * 128;
  const int ks = blockIdx.y;
  const int q = lane >> 4, n16 = lane & 15;
  const int qe = q & 1;
  const bool qlt2 = (q < 2);
  const int a1off = qlt2 ? 0 : 4096;        // [h|m]
  const int a2off = qlt2 ? 4096 : 0;        // [m|h]
  const int a3off = qlt2 ? 8192 : 0;        // [l|h]

  f32x4 acc[2][8];
#pragma unroll
  for (int rt = 0; rt < 2; ++rt)
#pragma unroll
    for (int h = 0; h < 8; ++h) acc[rt][h] = (f32x4){0.f, 0.f, 0.f, 0.f};

  for (int win = 0; win < 4; ++win) {
    const int dbase = ks * 128 + win * 32;
    __syncthreads();
    // stage x: 1024 chunks of 16B, flat [oct][row][half]
#pragma unroll
    for (int i = 0; i < 4; ++i) {
      int c = i * 256 + t;
      int u = c >> 1, half = c & 1;
      int oct = u >> 7, row = u & 127;
      stage16(x + (size_t)(r0 + row) * 1024 + dbase + oct * 8 + half * 4,
              sXf + (i * 256 + w * 64) * 4);
    }
    // stage B: 1536 chunks of 16B, flat [a][oct][col]
#pragma unroll
    for (int i = 0; i < 6; ++i) {
      int c = i * 256 + t;
      int a = c >> 9, rem = c & 511;
      int oct = rem >> 7, col = rem & 127;
      const unsigned short* Wa = (a == 0) ? Wth : ((a == 1) ? Wtm : Wtl);
      stage16((const float*)(Wa + (size_t)col * 1024 + dbase + oct * 8),
              (float*)sB + (i * 256 + w * 64) * 4);
    }
    __syncthreads();

#pragma unroll
    for (int dc2 = 0; dc2 < 2; ++dc2) {
      const int oct = dc2 * 2 + qe;
      bf16x8 av1[2], av3[2];
#pragma unroll
      for (int rt = 0; rt < 2; ++rt) {
        const int row = w * 32 + rt * 16 + n16;
        const float* xp = sXf + (oct * 128 + row) * 8;
        float4 xa = *(const float4*)(xp);
        float4 xb = *(const float4*)(xp + 4);
        float xf[8] = {xa.x, xa.y, xa.z, xa.w, xb.x, xb.y, xb.z, xb.w};
        unsigned short s1[8], s3[8];
#pragma unroll
        for (int j = 0; j < 8; ++j) {
          unsigned short hh, mm, ll;
          split3(xf[j], hh, mm, ll);
          s1[j] = qlt2 ? hh : mm;
          s3[j] = qlt2 ? hh : ll;
        }
        av1[rt] = *(bf16x8*)s1;
        av3[rt] = *(bf16x8*)s3;
      }
#pragma unroll
      for (int h = 0; h < 8; ++h) {
        const int u = oct * 128 + h * 16 + n16;
        bf16x8 b1 = *(const bf16x8*)(sB + (a1off + u * 8));
        bf16x8 b2 = *(const bf16x8*)(sB + (a2off + u * 8));
        bf16x8 b3 = *(const bf16x8*)(sB + (a3off + u * 8));
#pragma unroll
        for (int rt = 0; rt < 2; ++rt) {
          acc[rt][h] = __builtin_amdgcn_mfma_f32_16x16x32_bf16(av1[rt], b1, acc[rt][h], 0, 0, 0);
          acc[rt][h] = __builtin_amdgcn_mfma_f32_16x16x32_bf16(av1[rt], b2, acc[rt][h], 0, 0, 0);
          acc[rt][h] = __builtin_amdgcn_mfma_f32_16x16x32_bf16(av3[rt], b3, acc[rt][h], 0, 0, 0);
        }
      }
    }
  }

  float* po = part + ((size_t)ks * 8192 + r0) * 128;
#pragma unroll
  for (int rt = 0; rt < 2; ++rt)
#pragma unroll
    for (int h = 0; h < 8; ++h)
#pragma unroll
      for (int r = 0; r < 4; ++r)
        po[(size_t)(w * 32 + rt * 16 + q * 4 + r) * 128 + h * 16 + n16] =
            acc[rt][h][r];
}

// ---------------- K3b: combine 8 K-slices - mu*colsum, emit bf16 splits -----
__global__ __launch_bounds__(256) void k_combine(const float* __restrict__ part,
                                                 const float* __restrict__ mu,
                                                 const float* __restrict__ csum,
                                                 unsigned short* __restrict__ ph,
                                                 unsigned short* __restrict__ pm,
                                                 unsigned short* __restrict__ pl) {
  int idx = blockIdx.x * 256 + threadIdx.x;   // f4 index, 262144 total
  int row = idx >> 5, c4 = (idx & 31) * 4;
  float4 a = {0.f, 0.f, 0.f, 0.f};
#pragma unroll
  for (int s = 0; s < 8; ++s) {
    float4 p = *(const float4*)(part + ((size_t)s * 8192 + row) * 128 + c4);
    a.x += p.x; a.y += p.y; a.z += p.z; a.w += p.w;
  }
  float4 cs = *(const float4*)(csum + c4);
  float m = mu[row];
  float o[4] = {a.x - m * cs.x, a.y - m * cs.y, a.z - m * cs.z, a.w - m * cs.w};
  unsigned short vh[4], vm[4], vl[4];
#pragma unroll
  for (int k = 0; k < 4; ++k) split3(o[k], vh[k], vm[k], vl[k]);
  int head = c4 >> 4, e0 = c4 & 15;
  size_t base = ((size_t)head * 8192 + row) * 16 + e0;
  *(short4*)(ph + base) = *(short4*)vh;
  *(short4*)(pm + base) = *(short4*)vm;
  *(short4*)(pl + base) = *(short4*)vl;
}

// ---------------- K4: MFMA argmax partials (bf16 splits) --------------------
// Grid (32 rowgroups, 8 heads, 4 code-quarters) x 256. Wave = 64 rows (4
// row-tiles, A-frags in regs, reused over 32 code-tiles). Per tile: 3 B-loads
// per variant + 3 MFMAs per row-tile. Per-lane codes ascend -> strict '>' =
// first max; cross-lane shfl_xor(w16) lexicographic; quarters merged in amred.
__global__ __launch_bounds__(256) void k_argmax(
    const unsigned short* __restrict__ ph, const unsigned short* __restrict__ pm,
    const unsigned short* __restrict__ pl, const unsigned short* __restrict__ ch,
    const unsigned short* __restrict__ cm, const unsigned short* __restrict__ cl,
    float* __restrict__ amv, int* __restrict__ ami) {
  const int t = threadIdx.x;
  const int lane = t & 63, w = t >> 6;
  const int h = blockIdx.y;
  const int z = blockIdx.z;
  const int r0 = blockIdx.x * 256 + w * 64;
  const int q = lane >> 4;
  const int n16 = lane & 15;
  const int ehalf = (q & 1) * 8;
  const bool qlt2 = (q < 2);

  const unsigned short* pa1 = qlt2 ? ph : pm;   // A1 = [h|m]
  const unsigned short* pa3 = qlt2 ? ph : pl;   // A3 = [h|l]
  bf16x8 a1[4], a3[4];
#pragma unroll
  for (int rt = 0; rt < 4; ++rt) {
    size_t off = ((size_t)h * 8192 + r0 + rt * 16 + n16) * 16 + ehalf;
    a1[rt] = *(const bf16x8*)(pa1 + off);
    a3[rt] = *(const bf16x8*)(pa3 + off);
  }

  float best[4][4];
  int   bidx[4][4];
#pragma unroll
  for (int rt = 0; rt < 4; ++rt)
#pragma unroll
    for (int r = 0; r < 4; ++r) { best[rt][r] = -3.402823466e38f; bidx[rt][r] = 0; }

  const unsigned short* pb1 = qlt2 ? ch : cm;   // B1 = [h|m]
  const unsigned short* pb2 = qlt2 ? cm : ch;   // B2 = [m|h]
  const unsigned short* pb3 = qlt2 ? cl : ch;   // B3 = [l|h]
  const size_t cbase = ((size_t)h * 2048 + z * 512) * 16;

  for (int tile = 0; tile < 32; ++tile) {
    size_t off = cbase + (size_t)(tile * 16 + n16) * 16 + ehalf;
    bf16x8 b1 = *(const bf16x8*)(pb1 + off);
    bf16x8 b2 = *(const bf16x8*)(pb2 + off);
    bf16x8 b3 = *(const bf16x8*)(pb3 + off);
    const int code = z * 512 + tile * 16 + n16;
#pragma unroll
    for (int rt = 0; rt < 4; ++rt) {
      f32x4 acc = {0.f, 0.f, 0.f, 0.f};
      acc = __builtin_amdgcn_mfma_f32_16x16x32_bf16(a1[rt], b1, acc, 0, 0, 0);
      acc = __builtin_amdgcn_mfma_f32_16x16x32_bf16(a1[rt], b2, acc, 0, 0, 0);
      acc = __builtin_amdgcn_mfma_f32_16x16x32_bf16(a3[rt], b3, acc, 0, 0, 0);
#pragma unroll
      for (int r = 0; r < 4; ++r)
        if (acc[r] > best[rt][r]) { best[rt][r] = acc[r]; bidx[rt][r] = code; }
    }
  }

#pragma unroll
  for (int off = 8; off >= 1; off >>= 1) {
#pragma unroll
    for (int rt = 0; rt < 4; ++rt)
#pragma unroll
      for (int r = 0; r < 4; ++r) {
        float ov = __shfl_xor(best[rt][r], off, 16);
        int   oi = __shfl_xor(bidx[rt][r], off, 16);
        if (ov > best[rt][r] || (ov == best[rt][r] && oi < bidx[rt][r])) {
          best[rt][r] = ov; bidx[rt][r] = oi;
        }
      }
  }
  if (n16 == 0) {
#pragma unroll
    for (int rt = 0; rt < 4; ++rt)
#pragma unroll
      for (int r = 0; r < 4; ++r) {
        int row = r0 + rt * 16 + q * 4 + r;
        size_t o = (size_t)z * 65536 + (size_t)row * 8 + h;
        amv[o] = best[rt][r]; ami[o] = bidx[rt][r];
      }
  }
}

// ---------------- K5: merge the four code-quarters --------------------------
__global__ __launch_bounds__(256) void k_amred(const float* __restrict__ amv,
                                               const int* __restrict__ ami,
                                               int* __restrict__ out) {
  int i = blockIdx.x * 256 + threadIdx.x;   // 65536
  float bv = amv[i]; int bi = ami[i];
#pragma unroll
  for (int z = 1; z < 4; ++z) {
    float v = amv[(size_t)z * 65536 + i];
    if (v > bv) { bv = v; bi = ami[(size_t)z * 65536 + i]; }
  }
  out[i] = bi;
}

extern "C" void kernel_launch(void* const* d_in, const int* in_sizes, int n_in,
                              void* d_out, int out_size, void* d_ws, size_t ws_size,
                              hipStream_t stream) {
  (void)in_sizes; (void)n_in; (void)out_size; (void)ws_size;
  const float* x  = (const float*)d_in[0];   // [4,2048,1024]
  const float* rp = (const float*)d_in[1];   // [8,1024,16]
  const float* cb = (const float*)d_in[2];   // [8,2048,16]
  int* out = (int*)d_out;                    // [8192,8] int32

  float* ws = (float*)d_ws;
  float*          csum = ws;                              // 128
  float*          mu   = ws + 128;                        // 8192
  float*          part = ws + 8320;                       // 8*8192*128
  unsigned short* Wth  = (unsigned short*)(ws + 8396928); // 131072 sh each
  unsigned short* Wtm  = (unsigned short*)(ws + 8462464);
  unsigned short* Wtl  = (unsigned short*)(ws + 8528000);
  unsigned short* ch   = (unsigned short*)(ws + 8593536); // 262144 sh each
  unsigned short* cm   = (unsigned short*)(ws + 8724608);
  unsigned short* cl   = (unsigned short*)(ws + 8855680);
  unsigned short* ph   = (unsigned short*)(ws + 8986752); // 1048576 sh each
  unsigned short* pm   = (unsigned short*)(ws + 9511040);
  unsigned short* pl   = (unsigned short*)(ws + 10035328);
  float*          amv  = ws + 10559616;                   // 262144
  int*            ami  = (int*)(ws + 10821760);           // 262144 (~44.3 MB)

  hipLaunchKernelGGL(k_cbnorm,  dim3(64),        dim3(256), 0, stream, cb, ch, cm, cl);
  hipLaunchKernelGGL(k_colsum,  dim3(8),         dim3(256), 0, stream, rp, csum);
  hipLaunchKernelGGL(k_wsplit,  dim3(512),       dim3(256), 0, stream, rp, Wth, Wtm, Wtl);
  hipLaunchKernelGGL(k_mu,      dim3(512),       dim3(256), 0, stream, x, mu);
  hipLaunchKernelGGL(k_proj,    dim3(64, 8),     dim3(256), 0, stream, x, Wth, Wtm, Wtl, part);
  hipLaunchKernelGGL(k_combine, dim3(1024),      dim3(256), 0, stream, part, mu, csum, ph, pm, pl);
  hipLaunchKernelGGL(k_argmax,  dim3(32, 8, 4),  dim3(256), 0, stream, ph, pm, pl, ch, cm, cl, amv, ami);
  hipLaunchKernelGGL(k_amred,   dim3(256),       dim3(256), 0, stream, amv, ami, out);
}